// Round 4
// baseline (40.875 us; speedup 1.0000x reference)
//
#include <hip/hip_runtime.h>

// Volume rendering composite forward — same-size ray packing + ILP-8.
// Class c = ray_idx % 4 (data counts cycle 32/64/128/256). Class-c rays get a
// (4<<c)-lane subgroup, 8 samples per lane, 16>>c rays per 64-lane wave; every
// wave covers 512 samples. 10 float4 loads per lane are issued before any use
// (MLP), then one segmented shfl scan + chained-exp compositing.
// Chunk loop + rem/alignment guards keep it correct for ANY counts.

__global__ __launch_bounds__(256) void vr_fwd_kernel(
    const float* __restrict__ sigmas,
    const float* __restrict__ rgbs,
    const float* __restrict__ deltas,
    const float* __restrict__ ts,
    const int*   __restrict__ rays_a,
    const float* __restrict__ thr_p,
    float* __restrict__ out,   // counts | opacity | depth | rgb | w
    int n_rays, int b0, int b1, int b2, int b3)
{
    const int wid  = (int)((blockIdx.x * 256u + threadIdx.x) >> 6);
    const int lane = (int)(threadIdx.x & 63u);
    if (wid >= b3) return;

    // class + class-local wave ordinal (wave-uniform branches)
    int cls, wloc;
    if      (wid < b0) { cls = 0; wloc = wid; }
    else if (wid < b1) { cls = 1; wloc = wid - b0; }
    else if (wid < b2) { cls = 2; wloc = wid - b1; }
    else               { cls = 3; wloc = wid - b2; }

    const int sgW    = 4 << cls;          // lanes per subgroup
    const int rpw    = 16 >> cls;         // rays per wave
    const int sgId   = lane >> (2 + cls);
    const int sgLane = lane & (sgW - 1);

    const int ray = (wloc * rpw + sgId) * 4 + cls;  // class c: rays with idx%4==c
    const bool have_ray = (ray < n_rays);

    int start = 0, count = 0;
    if (have_ray) {
        start = rays_a[ray * 3 + 1];
        count = rays_a[ray * 3 + 2];
    }
    const float thr = thr_p[0];
    const bool  al4 = ((start & 3) == 0);   // float4 alignment guard

    float* __restrict__ out_counts  = out;
    float* __restrict__ out_opacity = out + n_rays;
    float* __restrict__ out_depth   = out + 2 * n_rays;
    float* __restrict__ out_rgb     = out + 3 * n_rays;
    float* __restrict__ out_w       = out + 6 * n_rays;

    float carry = 0.0f;
    float acc_n = 0.0f, acc_op = 0.0f, acc_d = 0.0f;
    float acc_r = 0.0f, acc_g = 0.0f, acc_b = 0.0f;

    for (int base = 0; base < count; base += sgW * 8) {
        const int li  = base + sgLane * 8;  // ray-local first sample of my 8
        const int gi  = start + li;
        const int rem = count - li;         // how many of my 8 are real

        float sd[8], tv[8], cr[8], cg[8], cb[8];
        #pragma unroll
        for (int k = 0; k < 8; ++k) { sd[k]=0.f; tv[k]=0.f; cr[k]=0.f; cg[k]=0.f; cb[k]=0.f; }

        if (al4 && rem >= 8) {
            // 10 float4 loads issued before any dependent use
            const float4 S0 = *reinterpret_cast<const float4*>(sigmas + gi);
            const float4 S1 = *reinterpret_cast<const float4*>(sigmas + gi + 4);
            const float4 D0 = *reinterpret_cast<const float4*>(deltas + gi);
            const float4 D1 = *reinterpret_cast<const float4*>(deltas + gi + 4);
            const float4 T0 = *reinterpret_cast<const float4*>(ts + gi);
            const float4 T1 = *reinterpret_cast<const float4*>(ts + gi + 4);
            const float4* rp = reinterpret_cast<const float4*>(rgbs + 3 * gi);
            const float4 R0 = rp[0], R1 = rp[1], R2 = rp[2];
            const float4 R3 = rp[3], R4 = rp[4], R5 = rp[5];

            sd[0]=S0.x*D0.x; sd[1]=S0.y*D0.y; sd[2]=S0.z*D0.z; sd[3]=S0.w*D0.w;
            sd[4]=S1.x*D1.x; sd[5]=S1.y*D1.y; sd[6]=S1.z*D1.z; sd[7]=S1.w*D1.w;
            tv[0]=T0.x; tv[1]=T0.y; tv[2]=T0.z; tv[3]=T0.w;
            tv[4]=T1.x; tv[5]=T1.y; tv[6]=T1.z; tv[7]=T1.w;
            cr[0]=R0.x; cg[0]=R0.y; cb[0]=R0.z;
            cr[1]=R0.w; cg[1]=R1.x; cb[1]=R1.y;
            cr[2]=R1.z; cg[2]=R1.w; cb[2]=R2.x;
            cr[3]=R2.y; cg[3]=R2.z; cb[3]=R2.w;
            cr[4]=R3.x; cg[4]=R3.y; cb[4]=R3.z;
            cr[5]=R3.w; cg[5]=R4.x; cb[5]=R4.y;
            cr[6]=R4.z; cg[6]=R4.w; cb[6]=R5.x;
            cr[7]=R5.y; cg[7]=R5.z; cb[7]=R5.w;
        } else if (rem > 0) {
            #pragma unroll
            for (int k = 0; k < 8; ++k) {
                if (k < rem) {
                    sd[k] = sigmas[gi + k] * deltas[gi + k];
                    tv[k] = ts[gi + k];
                    cr[k] = rgbs[3 * (gi + k) + 0];
                    cg[k] = rgbs[3 * (gi + k) + 1];
                    cb[k] = rgbs[3 * (gi + k) + 2];
                }
            }
        }

        // local inclusive prefix over my 8 samples
        float p[8];
        p[0] = sd[0];
        #pragma unroll
        for (int k = 1; k < 8; ++k) p[k] = p[k - 1] + sd[k];

        // subgroup-wide inclusive scan of lane totals (log2(sgW) steps)
        float sc = p[7];
        for (int off = 1; off < sgW; off <<= 1) {
            const float up = __shfl_up(sc, off, sgW);
            if (sgLane >= off) sc += up;
        }
        const float sg_total = __shfl(sc, sgW - 1, sgW);
        const float lex = carry + (sc - p[7]);   // exclusive prefix before my 8
        carry += sg_total;

        // T chain: one exp for the lane base + one exp(-sd) per element
        float T = __expf(-lex);
        float wv[8];
        #pragma unroll
        for (int k = 0; k < 8; ++k) {
            const float e     = __expf(-sd[k]);
            const bool  alive = (T >= thr);
            const float w     = alive ? (1.0f - e) * T : 0.0f;
            wv[k] = w;
            if (alive && k < rem) acc_n += 1.0f;
            acc_op += w;
            acc_d  += w * tv[k];
            acc_r  += w * cr[k];
            acc_g  += w * cg[k];
            acc_b  += w * cb[k];
            T *= e;
        }

        if (al4 && rem >= 8) {
            *reinterpret_cast<float4*>(out_w + gi) =
                make_float4(wv[0], wv[1], wv[2], wv[3]);
            *reinterpret_cast<float4*>(out_w + gi + 4) =
                make_float4(wv[4], wv[5], wv[6], wv[7]);
        } else if (rem > 0) {
            #pragma unroll
            for (int k = 0; k < 8; ++k)
                if (k < rem) out_w[gi + k] = wv[k];
        }
    }

    // subgroup reduce (leader = sgLane 0 gets the true sum)
    for (int off = sgW >> 1; off > 0; off >>= 1) {
        acc_n  += __shfl_down(acc_n,  off, sgW);
        acc_op += __shfl_down(acc_op, off, sgW);
        acc_d  += __shfl_down(acc_d,  off, sgW);
        acc_r  += __shfl_down(acc_r,  off, sgW);
        acc_g  += __shfl_down(acc_g,  off, sgW);
        acc_b  += __shfl_down(acc_b,  off, sgW);
    }

    if (sgLane == 0 && have_ray) {
        out_counts[ray]      = acc_n;     // total_samples stored as float
        out_opacity[ray]     = acc_op;
        out_depth[ray]       = acc_d;
        out_rgb[ray * 3 + 0] = acc_r;
        out_rgb[ray * 3 + 1] = acc_g;
        out_rgb[ray * 3 + 2] = acc_b;
    }
}

extern "C" void kernel_launch(void* const* d_in, const int* in_sizes, int n_in,
                              void* d_out, int out_size, void* d_ws, size_t ws_size,
                              hipStream_t stream) {
    const float* sigmas = (const float*)d_in[0];
    const float* rgbs   = (const float*)d_in[1];
    const float* deltas = (const float*)d_in[2];
    const float* ts     = (const float*)d_in[3];
    const int*   rays_a = (const int*)d_in[4];
    const float* thr    = (const float*)d_in[5];

    const int n_rays = in_sizes[4] / 3;
    float* out = (float*)d_out;

    // waves per class: class c holds rays with idx%4==c, packed 16>>c per wave
    int b[4], cum = 0;
    for (int c = 0; c < 4; ++c) {
        int Kc = (n_rays - c + 3) / 4;          // rays in class c
        if (Kc < 0) Kc = 0;
        const int rpw = 16 >> c;
        cum += (Kc + rpw - 1) / rpw;
        b[c] = cum;
    }
    const int total_waves = b[3];
    const int blocks = (total_waves + 3) / 4;   // 4 waves per 256-thread block

    vr_fwd_kernel<<<blocks, 256, 0, stream>>>(sigmas, rgbs, deltas, ts, rays_a,
                                              thr, out, n_rays,
                                              b[0], b[1], b[2], b[3]);
}